// Round 7
// baseline (272.844 us; speedup 1.0000x reference)
//
#include <hip/hip_runtime.h>
#include <math.h>

#define TILE 4096          // edges per partition tile
#define CSHIFT 11          // coarse bucket = dst >> 11  (2048 nodes)
#define CMASK 2047
#define NCMAX 64

// ---------- helpers ----------

__device__ __forceinline__ unsigned int pack_bf16(float a, float b) {
  unsigned int ua = __float_as_uint(a);
  ua += 0x7FFFu + ((ua >> 16) & 1u);
  unsigned int ub = __float_as_uint(b);
  ub += 0x7FFFu + ((ub >> 16) & 1u);
  return (ua >> 16) | (ub & 0xFFFF0000u);
}

// acc[0..7] += bf16x8(hv)
__device__ __forceinline__ void add8(float* acc, uint4 hv) {
  unsigned int u[4] = {hv.x, hv.y, hv.z, hv.w};
#pragma unroll
  for (int i = 0; i < 4; ++i) {
    acc[2 * i]     += __uint_as_float(u[i] << 16);
    acc[2 * i + 1] += __uint_as_float(u[i] & 0xFFFF0000u);
  }
}

__device__ __forceinline__ void fma4(float4& acc, float s, const float4& w) {
  acc.x = fmaf(s, w.x, acc.x);
  acc.y = fmaf(s, w.y, acc.y);
  acc.z = fmaf(s, w.z, acc.z);
  acc.w = fmaf(s, w.w, acc.w);
}

// ---------- CSR build: two-level LDS-staged split ----------

__global__ void zero_kernel(int* __restrict__ p, int n) {
  int i = blockIdx.x * blockDim.x + threadIdx.x;
  if (i < n) p[i] = 0;
}

__global__ __launch_bounds__(256) void coarse_hist_kernel(const int* __restrict__ dst,
    int* __restrict__ ccnt, int e) {
  __shared__ int h[NCMAX];
  if (threadIdx.x < NCMAX) h[threadIdx.x] = 0;
  __syncthreads();
  for (int i = blockIdx.x * 256 + threadIdx.x; i < e; i += gridDim.x * 256)
    atomicAdd(&h[dst[i] >> CSHIFT], 1);
  __syncthreads();
  if (threadIdx.x < NCMAX && h[threadIdx.x])
    atomicAdd(&ccnt[threadIdx.x * 16], h[threadIdx.x]);
}

// single wave: exclusive scan of nc coarse counts; init cursors; off[n]=e
__global__ __launch_bounds__(64) void coarse_scan_kernel(const int* __restrict__ ccnt,
    int* __restrict__ coff, int* __restrict__ ccur, int* __restrict__ off,
    int nc, int n, int e) {
  int t = threadIdx.x;
  int v = (t < nc) ? ccnt[t * 16] : 0;
  int incl = v;
#pragma unroll
  for (int ofs = 1; ofs < 64; ofs <<= 1) {
    int w = __shfl_up(incl, ofs);
    if (t >= ofs) incl += w;
  }
  int excl = incl - v;
  if (t < nc) { coff[t] = excl; ccur[t * 16] = excl; }
  if (t == nc - 1) coff[nc] = incl;
  if (t == 0) off[n] = e;
}

// LDS-staged partition: sort a 4096-edge tile by coarse bucket in LDS, reserve
// a global range per bucket with ONE atomic, stream out contiguous segments.
__global__ __launch_bounds__(256) void coarse_partition_kernel(const int* __restrict__ src,
    const int* __restrict__ dst, int* __restrict__ ccur,
    unsigned int* __restrict__ packed, int e) {
  __shared__ unsigned int stage[TILE];
  __shared__ unsigned char bid[TILE];
  __shared__ int hist[NCMAX], excl[NCMAX], gbase[NCMAX], lcur[NCMAX];
  int ntiles = (e + TILE - 1) / TILE;
  for (int tile = blockIdx.x; tile < ntiles; tile += gridDim.x) {
    int i0 = tile * TILE;
    int cnt = e - i0; if (cnt > TILE) cnt = TILE;
    if (threadIdx.x < NCMAX) hist[threadIdx.x] = 0;
    __syncthreads();
    int myS[16], myD[16];
#pragma unroll
    for (int k = 0; k < 16; ++k) {
      int li = threadIdx.x + k * 256;
      if (li < cnt) {
        myS[k] = src[i0 + li];
        myD[k] = dst[i0 + li];
        atomicAdd(&hist[myD[k] >> CSHIFT], 1);
      }
    }
    __syncthreads();
    if (threadIdx.x < NCMAX) {  // wave 0: scan 64 buckets
      int t = threadIdx.x;
      int v = hist[t];
      int incl = v;
#pragma unroll
      for (int ofs = 1; ofs < 64; ofs <<= 1) {
        int w = __shfl_up(incl, ofs);
        if (t >= ofs) incl += w;
      }
      excl[t] = incl - v;
      lcur[t] = incl - v;
    }
    __syncthreads();
#pragma unroll
    for (int k = 0; k < 16; ++k) {
      int li = threadIdx.x + k * 256;
      if (li < cnt) {
        int c = myD[k] >> CSHIFT;
        int p = atomicAdd(&lcur[c], 1);
        stage[p] = (unsigned int)myS[k] | ((unsigned int)(myD[k] & CMASK) << 17);
        bid[p] = (unsigned char)c;
      }
    }
    __syncthreads();
    if (threadIdx.x < NCMAX) {
      int t = threadIdx.x;
      int cc = lcur[t] - excl[t];
      gbase[t] = cc ? atomicAdd(&ccur[t * 16], cc) : 0;
    }
    __syncthreads();
    for (int i = threadIdx.x; i < cnt; i += 256) {
      int c = bid[i];
      packed[gbase[c] + (i - excl[c])] = stage[i];
    }
    __syncthreads();  // protect hist/stage reuse
  }
}

// one block per coarse bucket: counting sort 2048 node sub-buckets -> csr, off, dinv.
__global__ __launch_bounds__(512) void csr_fine_kernel(const unsigned int* __restrict__ packed,
    const int* __restrict__ coff, int* __restrict__ off, float* __restrict__ dinv,
    int* __restrict__ csr, int n) {
  __shared__ int lh[2048];
  __shared__ int lsum[512];
  int b = blockIdx.x;
  int t = threadIdx.x;
  int e0 = coff[b], e1 = coff[b + 1];
  int node0 = b << CSHIFT;
  for (int i = t; i < 2048; i += 512) lh[i] = 0;
  __syncthreads();
  for (int i = e0 + t; i < e1; i += 512) atomicAdd(&lh[packed[i] >> 17], 1);
  __syncthreads();
  int base = t * 4;
  int v0 = lh[base], v1 = lh[base + 1], v2 = lh[base + 2], v3 = lh[base + 3];
  int tsum = v0 + v1 + v2 + v3;
  lsum[t] = tsum;
  __syncthreads();
  for (int ofs = 1; ofs < 512; ofs <<= 1) {
    int add = (t >= ofs) ? lsum[t - ofs] : 0;
    __syncthreads();
    lsum[t] += add;
    __syncthreads();
  }
  int ex = lsum[t] - tsum;
  int exc0 = ex, exc1 = ex + v0, exc2 = ex + v0 + v1, exc3 = ex + v0 + v1 + v2;
  lh[base] = exc0; lh[base + 1] = exc1; lh[base + 2] = exc2; lh[base + 3] = exc3;
  int node = node0 + base;
  if (node < n)     { off[node]     = e0 + exc0; dinv[node]     = rsqrtf((float)(v0 + 1)); }
  if (node + 1 < n) { off[node + 1] = e0 + exc1; dinv[node + 1] = rsqrtf((float)(v1 + 1)); }
  if (node + 2 < n) { off[node + 2] = e0 + exc2; dinv[node + 2] = rsqrtf((float)(v2 + 1)); }
  if (node + 3 < n) { off[node + 3] = e0 + exc3; dinv[node + 3] = rsqrtf((float)(v3 + 1)); }
  __syncthreads();
  for (int i = e0 + t; i < e1; i += 512) {
    unsigned int p = packed[i];
    int nl = p >> 17;
    int pos = atomicAdd(&lh[nl], 1);
    csr[e0 + pos] = (int)(p & 0x1FFFFu);
  }
}

// ---------- h1' = dinv * (x @ W1), output bf16 ----------
// One wave per row; lane = output column; W1 entirely in VGPRs (128/lane),
// loaded once per wave and amortized over ~33 rows. x row streamed as 32
// same-address float4 broadcasts. No LDS, no barriers.
__global__ __launch_bounds__(256, 3) void gemm1_kernel(const float* __restrict__ x,
    const float* __restrict__ W1, const float* __restrict__ dinv,
    unsigned int* __restrict__ h1, int n) {
  int lane = threadIdx.x & 63;
  int wid = blockIdx.x * 4 + (threadIdx.x >> 6);
  int nwaves = gridDim.x * 4;
  float w[128];
#pragma unroll
  for (int k = 0; k < 128; ++k) w[k] = W1[k * 64 + lane];
  for (int row = wid; row < n; row += nwaves) {
    const float4* xr = (const float4*)(x + (size_t)row * 128);
    float acc = 0.f;
#pragma unroll
    for (int kq = 0; kq < 32; ++kq) {
      float4 xv = xr[kq];
      acc = fmaf(xv.x, w[4 * kq + 0], acc);
      acc = fmaf(xv.y, w[4 * kq + 1], acc);
      acc = fmaf(xv.z, w[4 * kq + 2], acc);
      acc = fmaf(xv.w, w[4 * kq + 3], acc);
    }
    float val = dinv[row] * acc;
    float pv = __shfl_xor(val, 1);
    if (!(lane & 1)) {
      h1[(size_t)row * 32 + (lane >> 1)] = pack_bf16(val, pv);
    }
  }
}

// ---------- aggregation ----------
// 16 edge-slots x 4 feature-lanes per wave. h rows dinv-prefolded (h'=dinv*h).
// acc = h'[node] + sum_{e:dst=node} h'[src];  result = dinv[node]*acc.
// Recursive-halving shfl reduce leaves ONE feature per lane (static reg indices).
// EPI=1: out = bf16( dinv * tanh(result + bias) ); EPI=0: out = bf16(result).
template <int EPI>
__global__ __launch_bounds__(256) void agg_kernel(const uint4* __restrict__ h4,
    const int* __restrict__ off, const int* __restrict__ csr,
    const float* __restrict__ dinv, const float* __restrict__ bias,
    unsigned int* __restrict__ out, int n) {
  int node = blockIdx.x * 4 + (threadIdx.x >> 6);
  if (node >= n) return;
  int lane = threadIdx.x & 63;
  int j = lane >> 2;   // edge slot 0..15
  int l = lane & 3;    // feature quarter (16 bf16 = 32B = 2 uint4)
  float acc[16];
#pragma unroll
  for (int i = 0; i < 16; ++i) acc[i] = 0.f;
  if (j == 0) {  // self loop
    uint4 a = h4[(size_t)node * 8 + l * 2];
    uint4 b = h4[(size_t)node * 8 + l * 2 + 1];
    add8(acc, a);
    add8(acc + 8, b);
  }
  int e1 = off[node + 1];
  for (int ee = off[node] + j; ee < e1; ee += 16) {
    int s = __builtin_nontemporal_load(&csr[ee]);
    uint4 a = h4[(size_t)s * 8 + l * 2];
    uint4 b = h4[(size_t)s * 8 + l * 2 + 1];
    add8(acc, a);
    add8(acc + 8, b);
  }
  // recursive-halving reduce over the 16 slots; feature count 16 -> 1
#pragma unroll
  for (int i = 0; i < 8; ++i) {
    float tlo = acc[i]     + __shfl_xor(acc[i], 4);
    float thi = acc[i + 8] + __shfl_xor(acc[i + 8], 4);
    acc[i] = (j & 1) ? thi : tlo;
  }
#pragma unroll
  for (int i = 0; i < 4; ++i) {
    float tlo = acc[i]     + __shfl_xor(acc[i], 8);
    float thi = acc[i + 4] + __shfl_xor(acc[i + 4], 8);
    acc[i] = (j & 2) ? thi : tlo;
  }
#pragma unroll
  for (int i = 0; i < 2; ++i) {
    float tlo = acc[i]     + __shfl_xor(acc[i], 16);
    float thi = acc[i + 2] + __shfl_xor(acc[i + 2], 16);
    acc[i] = (j & 4) ? thi : tlo;
  }
  float a0, a1;
  a0 = acc[0] + __shfl_xor(acc[0], 32);
  a1 = acc[1] + __shfl_xor(acc[1], 32);
  float a = (j & 8) ? a1 : a0;
  // this lane now owns feature f = l*16 + j0*8 + j1*4 + j2*2 + j3
  int f = l * 16 + ((j & 1) << 3) + ((j & 2) << 1) + ((j >> 2) & 1) * 2 + ((j >> 3) & 1);
  float di = dinv[node];
  float val;
  if (EPI) {
    val = di * tanhf(fmaf(di, a, bias[f]));
  } else {
    val = di * a;
  }
  // pack feature pairs (f even with f+1, partner lane = lane^32) and store
  float pv = __shfl_xor(val, 32);
  if (!(j & 8)) {  // f even
    unsigned int w = pack_bf16(val, pv);
    int half = l * 8 + ((j & 1) << 2) + (j & 2) + ((j >> 2) & 1);  // f/2
    out[(size_t)node * 32 + half] = w;
  }
}

// ---------- final: mean/logvar GEMMs + reparam ----------
__global__ __launch_bounds__(256) void final_kernel(const unsigned int* __restrict__ aggb,
    const float* __restrict__ Wm, const float* __restrict__ bm,
    const float* __restrict__ Wv, const float* __restrict__ bv,
    const float* __restrict__ noise, float* __restrict__ outZ,
    float* __restrict__ outM, float* __restrict__ outLv, int n) {
  __shared__ float WmS[64 * 32];
  __shared__ float WvS[64 * 32];
  __shared__ float aggS[64 * 68];  // stride 68 breaks bank conflicts
  for (int i = threadIdx.x; i < 64 * 8; i += 256) {
    ((float4*)WmS)[i] = ((const float4*)Wm)[i];
    ((float4*)WvS)[i] = ((const float4*)Wv)[i];
  }
  int row0 = blockIdx.x * 64;
  int nrow = n - row0; if (nrow > 64) nrow = 64;
  for (int i = threadIdx.x; i < 64 * 16; i += 256) {
    int r = i >> 4, g = i & 15;
    uint2 u = make_uint2(0u, 0u);
    if (r < nrow) u = ((const uint2*)aggb)[(size_t)(row0 + r) * 16 + g];
    float* d = &aggS[r * 68 + g * 4];
    d[0] = __uint_as_float(u.x << 16);
    d[1] = __uint_as_float(u.x & 0xFFFF0000u);
    d[2] = __uint_as_float(u.y << 16);
    d[3] = __uint_as_float(u.y & 0xFFFF0000u);
  }
  __syncthreads();
  int c4 = (threadIdx.x & 7) * 4;
  int r2 = (threadIdx.x >> 3) * 2;
  float4 am[2], av[2];
#pragma unroll
  for (int i = 0; i < 2; ++i) {
    am[i] = make_float4(0.f, 0.f, 0.f, 0.f);
    av[i] = make_float4(0.f, 0.f, 0.f, 0.f);
  }
#pragma unroll 4
  for (int kq = 0; kq < 16; ++kq) {
    float4 xa[2], wm[4], wv[4];
#pragma unroll
    for (int i = 0; i < 2; ++i) xa[i] = *(const float4*)&aggS[(r2 + i) * 68 + kq * 4];
#pragma unroll
    for (int q = 0; q < 4; ++q) {
      wm[q] = *(const float4*)&WmS[(kq * 4 + q) * 32 + c4];
      wv[q] = *(const float4*)&WvS[(kq * 4 + q) * 32 + c4];
    }
#pragma unroll
    for (int i = 0; i < 2; ++i) {
      fma4(am[i], xa[i].x, wm[0]); fma4(am[i], xa[i].y, wm[1]);
      fma4(am[i], xa[i].z, wm[2]); fma4(am[i], xa[i].w, wm[3]);
      fma4(av[i], xa[i].x, wv[0]); fma4(av[i], xa[i].y, wv[1]);
      fma4(av[i], xa[i].z, wv[2]); fma4(av[i], xa[i].w, wv[3]);
    }
  }
  float4 bmv = *(const float4*)&bm[c4];
  float4 bvv = *(const float4*)&bv[c4];
#pragma unroll
  for (int i = 0; i < 2; ++i) {
    int row = row0 + r2 + i;
    if (row < n) {
      float4 m = am[i]; m.x += bmv.x; m.y += bmv.y; m.z += bmv.z; m.w += bmv.w;
      float4 v = av[i]; v.x += bvv.x; v.y += bvv.y; v.z += bvv.z; v.w += bvv.w;
      size_t oi = (size_t)row * 8 + (threadIdx.x & 7);
      float4 nz = ((const float4*)noise)[oi];
      float4 z;
      z.x = fmaf(nz.x, expf(0.5f * v.x), m.x);
      z.y = fmaf(nz.y, expf(0.5f * v.y), m.y);
      z.z = fmaf(nz.z, expf(0.5f * v.z), m.z);
      z.w = fmaf(nz.w, expf(0.5f * v.w), m.w);
      ((float4*)outZ)[oi] = z;
      ((float4*)outM)[oi] = m;
      ((float4*)outLv)[oi] = v;
    }
  }
}

// ---------- launch ----------

extern "C" void kernel_launch(void* const* d_in, const int* in_sizes, int n_in,
                              void* d_out, int out_size, void* d_ws, size_t ws_size,
                              hipStream_t stream) {
  const float* x     = (const float*)d_in[0];
  const int*   edge  = (const int*)d_in[1];
  const float* W1    = (const float*)d_in[2];
  const float* b1    = (const float*)d_in[3];
  const float* Wm    = (const float*)d_in[4];
  const float* bm    = (const float*)d_in[5];
  const float* Wv    = (const float*)d_in[6];
  const float* bv    = (const float*)d_in[7];
  const float* noise = (const float*)d_in[8];
  int n = in_sizes[0] / 128;
  int e = in_sizes[1] / 2;
  const int* src = edge;
  const int* dst = edge + e;
  int nc = (n + CMASK) >> CSHIFT;   // 49 coarse buckets of 2048 nodes

  // workspace layout (int units, 16B-aligned segments)
  int* ccnt = (int*)d_ws;                          // NCMAX*16 (1 per 64B line)
  int* ccur = ccnt + NCMAX * 16;                   // NCMAX*16
  int* coff = ccur + NCMAX * 16;                   // NCMAX+1 (+pad)
  int* off  = coff + (NCMAX + 4);                  // n+1 (+pad)
  float* dinv = (float*)(off + ((n + 4) & ~3));    // n
  unsigned int* packed = (unsigned int*)(dinv + ((n + 3) & ~3)); // e
  int* csr  = (int*)(packed + ((e + 3) & ~3));     // e
  unsigned int* h1b = (unsigned int*)(csr + ((e + 3) & ~3)); // n*32 (bf16 h1')
  unsigned int* hb  = h1b + (size_t)n * 32;                  // n*32 (bf16 h')
  unsigned int* aggb = hb + (size_t)n * 32;                  // n*32 (bf16 agg2)

  float* outZ  = (float*)d_out;
  float* outM  = outZ + (size_t)n * 32;
  float* outLv = outM + (size_t)n * 32;

  int ntiles = (e + TILE - 1) / TILE;

  zero_kernel<<<(NCMAX * 16 + 255) / 256, 256, 0, stream>>>(ccnt, NCMAX * 16);
  coarse_hist_kernel<<<256, 256, 0, stream>>>(dst, ccnt, e);
  coarse_scan_kernel<<<1, 64, 0, stream>>>(ccnt, coff, ccur, off, nc, n, e);
  coarse_partition_kernel<<<ntiles, 256, 0, stream>>>(src, dst, ccur, packed, e);
  csr_fine_kernel<<<nc, 512, 0, stream>>>(packed, coff, off, dinv, csr, n);
  gemm1_kernel<<<768, 256, 0, stream>>>(x, W1, dinv, h1b, n);
  agg_kernel<1><<<(n + 3) / 4, 256, 0, stream>>>((const uint4*)h1b, off, csr, dinv, b1, hb, n);
  agg_kernel<0><<<(n + 3) / 4, 256, 0, stream>>>((const uint4*)hb, off, csr, dinv, b1, aggb, n);
  final_kernel<<<(n + 63) / 64, 256, 0, stream>>>(aggb, Wm, bm, Wv, bv, noise, outZ, outM, outLv, n);
}

// Round 8
// 223.173 us; speedup vs baseline: 1.2226x; 1.2226x over previous
//
#include <hip/hip_runtime.h>
#include <math.h>

#define TILE 4096          // edges per partition tile
#define CSHIFT 11          // coarse bucket = dst >> 11  (2048 nodes)
#define CMASK 2047
#define NCMAX 64

// ---------- helpers ----------

__device__ __forceinline__ unsigned int pack_bf16(float a, float b) {
  unsigned int ua = __float_as_uint(a);
  ua += 0x7FFFu + ((ua >> 16) & 1u);
  unsigned int ub = __float_as_uint(b);
  ub += 0x7FFFu + ((ub >> 16) & 1u);
  return (ua >> 16) | (ub & 0xFFFF0000u);
}

// acc[0..7] += bf16x8(hv)
__device__ __forceinline__ void add8(float* acc, uint4 hv) {
  unsigned int u[4] = {hv.x, hv.y, hv.z, hv.w};
#pragma unroll
  for (int i = 0; i < 4; ++i) {
    acc[2 * i]     += __uint_as_float(u[i] << 16);
    acc[2 * i + 1] += __uint_as_float(u[i] & 0xFFFF0000u);
  }
}

__device__ __forceinline__ void fma4(float4& acc, float s, const float4& w) {
  acc.x = fmaf(s, w.x, acc.x);
  acc.y = fmaf(s, w.y, acc.y);
  acc.z = fmaf(s, w.z, acc.z);
  acc.w = fmaf(s, w.w, acc.w);
}

// ---------- CSR build: two-level LDS-staged split ----------

__global__ void zero_kernel(int* __restrict__ p, int n) {
  int i = blockIdx.x * blockDim.x + threadIdx.x;
  if (i < n) p[i] = 0;
}

__global__ __launch_bounds__(256) void coarse_hist_kernel(const int* __restrict__ dst,
    int* __restrict__ ccnt, int e) {
  __shared__ int h[NCMAX];
  if (threadIdx.x < NCMAX) h[threadIdx.x] = 0;
  __syncthreads();
  for (int i = blockIdx.x * 256 + threadIdx.x; i < e; i += gridDim.x * 256)
    atomicAdd(&h[dst[i] >> CSHIFT], 1);
  __syncthreads();
  if (threadIdx.x < NCMAX && h[threadIdx.x])
    atomicAdd(&ccnt[threadIdx.x * 16], h[threadIdx.x]);
}

// single wave: exclusive scan of nc coarse counts; init cursors; off[n]=e
__global__ __launch_bounds__(64) void coarse_scan_kernel(const int* __restrict__ ccnt,
    int* __restrict__ coff, int* __restrict__ ccur, int* __restrict__ off,
    int nc, int n, int e) {
  int t = threadIdx.x;
  int v = (t < nc) ? ccnt[t * 16] : 0;
  int incl = v;
#pragma unroll
  for (int ofs = 1; ofs < 64; ofs <<= 1) {
    int w = __shfl_up(incl, ofs);
    if (t >= ofs) incl += w;
  }
  int excl = incl - v;
  if (t < nc) { coff[t] = excl; ccur[t * 16] = excl; }
  if (t == nc - 1) coff[nc] = incl;
  if (t == 0) off[n] = e;
}

// LDS-staged partition: sort a 4096-edge tile by coarse bucket in LDS, reserve
// a global range per bucket with ONE atomic, stream out contiguous segments.
__global__ __launch_bounds__(256) void coarse_partition_kernel(const int* __restrict__ src,
    const int* __restrict__ dst, int* __restrict__ ccur,
    unsigned int* __restrict__ packed, int e) {
  __shared__ unsigned int stage[TILE];
  __shared__ unsigned char bid[TILE];
  __shared__ int hist[NCMAX], excl[NCMAX], gbase[NCMAX], lcur[NCMAX];
  int ntiles = (e + TILE - 1) / TILE;
  for (int tile = blockIdx.x; tile < ntiles; tile += gridDim.x) {
    int i0 = tile * TILE;
    int cnt = e - i0; if (cnt > TILE) cnt = TILE;
    if (threadIdx.x < NCMAX) hist[threadIdx.x] = 0;
    __syncthreads();
    int myS[16], myD[16];
#pragma unroll
    for (int k = 0; k < 16; ++k) {
      int li = threadIdx.x + k * 256;
      if (li < cnt) {
        myS[k] = src[i0 + li];
        myD[k] = dst[i0 + li];
        atomicAdd(&hist[myD[k] >> CSHIFT], 1);
      }
    }
    __syncthreads();
    if (threadIdx.x < NCMAX) {  // wave 0: scan 64 buckets
      int t = threadIdx.x;
      int v = hist[t];
      int incl = v;
#pragma unroll
      for (int ofs = 1; ofs < 64; ofs <<= 1) {
        int w = __shfl_up(incl, ofs);
        if (t >= ofs) incl += w;
      }
      excl[t] = incl - v;
      lcur[t] = incl - v;
    }
    __syncthreads();
#pragma unroll
    for (int k = 0; k < 16; ++k) {
      int li = threadIdx.x + k * 256;
      if (li < cnt) {
        int c = myD[k] >> CSHIFT;
        int p = atomicAdd(&lcur[c], 1);
        stage[p] = (unsigned int)myS[k] | ((unsigned int)(myD[k] & CMASK) << 17);
        bid[p] = (unsigned char)c;
      }
    }
    __syncthreads();
    if (threadIdx.x < NCMAX) {
      int t = threadIdx.x;
      int cc = lcur[t] - excl[t];
      gbase[t] = cc ? atomicAdd(&ccur[t * 16], cc) : 0;
    }
    __syncthreads();
    for (int i = threadIdx.x; i < cnt; i += 256) {
      int c = bid[i];
      packed[gbase[c] + (i - excl[c])] = stage[i];
    }
    __syncthreads();  // protect hist/stage reuse
  }
}

// one block per coarse bucket: counting sort 2048 node sub-buckets -> csr, off, dinv.
__global__ __launch_bounds__(512) void csr_fine_kernel(const unsigned int* __restrict__ packed,
    const int* __restrict__ coff, int* __restrict__ off, float* __restrict__ dinv,
    int* __restrict__ csr, int n) {
  __shared__ int lh[2048];
  __shared__ int lsum[512];
  int b = blockIdx.x;
  int t = threadIdx.x;
  int e0 = coff[b], e1 = coff[b + 1];
  int node0 = b << CSHIFT;
  for (int i = t; i < 2048; i += 512) lh[i] = 0;
  __syncthreads();
  for (int i = e0 + t; i < e1; i += 512) atomicAdd(&lh[packed[i] >> 17], 1);
  __syncthreads();
  int base = t * 4;
  int v0 = lh[base], v1 = lh[base + 1], v2 = lh[base + 2], v3 = lh[base + 3];
  int tsum = v0 + v1 + v2 + v3;
  lsum[t] = tsum;
  __syncthreads();
  for (int ofs = 1; ofs < 512; ofs <<= 1) {
    int add = (t >= ofs) ? lsum[t - ofs] : 0;
    __syncthreads();
    lsum[t] += add;
    __syncthreads();
  }
  int ex = lsum[t] - tsum;
  int exc0 = ex, exc1 = ex + v0, exc2 = ex + v0 + v1, exc3 = ex + v0 + v1 + v2;
  lh[base] = exc0; lh[base + 1] = exc1; lh[base + 2] = exc2; lh[base + 3] = exc3;
  int node = node0 + base;
  if (node < n)     { off[node]     = e0 + exc0; dinv[node]     = rsqrtf((float)(v0 + 1)); }
  if (node + 1 < n) { off[node + 1] = e0 + exc1; dinv[node + 1] = rsqrtf((float)(v1 + 1)); }
  if (node + 2 < n) { off[node + 2] = e0 + exc2; dinv[node + 2] = rsqrtf((float)(v2 + 1)); }
  if (node + 3 < n) { off[node + 3] = e0 + exc3; dinv[node + 3] = rsqrtf((float)(v3 + 1)); }
  __syncthreads();
  for (int i = e0 + t; i < e1; i += 512) {
    unsigned int p = packed[i];
    int nl = p >> 17;
    int pos = atomicAdd(&lh[nl], 1);
    csr[e0 + pos] = (int)(p & 0x1FFFFu);
  }
}

// ---------- h1' = dinv * (x @ W1), output bf16 ----------
// 64-row tile, 4x4 register block per thread. Ws stored as bf16 pairs (16KB)
// + xs f32 swizzled (32KB) = 48KB LDS -> 3 blocks/CU. Grid-stride (768 blocks)
// so W is loaded/packed once per block.
__global__ __launch_bounds__(256) void gemm1_kernel(const float* __restrict__ x,
    const float* __restrict__ W1, const float* __restrict__ dinv,
    unsigned int* __restrict__ h1, int n) {
  __shared__ unsigned int Ws[128 * 32];  // 16 KB: W[k][c-pair] as bf16x2
  __shared__ float xs[64 * 128];         // 32 KB, float4-slot XOR swizzle
  for (int i = threadIdx.x; i < 128 * 32; i += 256) {
    float2 wv = ((const float2*)W1)[i];
    Ws[i] = pack_bf16(wv.x, wv.y);
  }
  int c4 = (threadIdx.x & 15) * 4;
  int r4 = (threadIdx.x >> 4) * 4;
  int cpair = c4 >> 1;  // uint index of first bf16-pair in a 32-pair row
  int ntiles = (n + 63) >> 6;
  for (int tile = blockIdx.x; tile < ntiles; tile += gridDim.x) {
    int row0 = tile * 64;
    int nrow = n - row0; if (nrow > 64) nrow = 64;
    __syncthreads();  // protects xs reuse (and covers initial Ws pack)
    for (int i = threadIdx.x; i < 64 * 32; i += 256) {
      int r = i >> 5, kq = i & 31;
      float4 v = make_float4(0.f, 0.f, 0.f, 0.f);
      if (r < nrow) v = ((const float4*)(x + (size_t)(row0 + r) * 128))[kq];
      int slot = r * 32 + (kq ^ ((r >> 2) & 3));
      *(float4*)&xs[slot * 4] = v;
    }
    __syncthreads();
    float4 acc[4];
#pragma unroll
    for (int i = 0; i < 4; ++i) acc[i] = make_float4(0.f, 0.f, 0.f, 0.f);
#pragma unroll 4
    for (int kq = 0; kq < 32; ++kq) {
      float4 xv[4], wv[4];
#pragma unroll
      for (int i = 0; i < 4; ++i) {
        int r = r4 + i;
        int slot = r * 32 + (kq ^ ((r >> 2) & 3));
        xv[i] = *(const float4*)&xs[slot * 4];
      }
#pragma unroll
      for (int q = 0; q < 4; ++q) {
        uint2 u = *(const uint2*)&Ws[(kq * 4 + q) * 32 + cpair];
        wv[q].x = __uint_as_float(u.x << 16);
        wv[q].y = __uint_as_float(u.x & 0xFFFF0000u);
        wv[q].z = __uint_as_float(u.y << 16);
        wv[q].w = __uint_as_float(u.y & 0xFFFF0000u);
      }
#pragma unroll
      for (int i = 0; i < 4; ++i) {
        fma4(acc[i], xv[i].x, wv[0]);
        fma4(acc[i], xv[i].y, wv[1]);
        fma4(acc[i], xv[i].z, wv[2]);
        fma4(acc[i], xv[i].w, wv[3]);
      }
    }
#pragma unroll
    for (int i = 0; i < 4; ++i) {
      int row = row0 + r4 + i;
      if (row < n) {
        float dv = dinv[row];
        uint2 pv;
        pv.x = pack_bf16(dv * acc[i].x, dv * acc[i].y);
        pv.y = pack_bf16(dv * acc[i].z, dv * acc[i].w);
        ((uint2*)h1)[(size_t)row * 16 + (threadIdx.x & 15)] = pv;
      }
    }
  }
}

// ---------- aggregation ----------
// 16 edge-slots x 4 feature-lanes per wave. h rows dinv-prefolded (h'=dinv*h).
// acc = h'[node] + sum_{e:dst=node} h'[src];  result = dinv[node]*acc.
// Recursive-halving shfl reduce leaves ONE feature per lane (static reg indices).
// EPI=1: out = bf16( dinv * tanh(result + bias) ); EPI=0: out = bf16(result).
template <int EPI>
__global__ __launch_bounds__(256) void agg_kernel(const uint4* __restrict__ h4,
    const int* __restrict__ off, const int* __restrict__ csr,
    const float* __restrict__ dinv, const float* __restrict__ bias,
    unsigned int* __restrict__ out, int n) {
  int node = blockIdx.x * 4 + (threadIdx.x >> 6);
  if (node >= n) return;
  int lane = threadIdx.x & 63;
  int j = lane >> 2;   // edge slot 0..15
  int l = lane & 3;    // feature quarter (16 bf16 = 32B = 2 uint4)
  float acc[16];
#pragma unroll
  for (int i = 0; i < 16; ++i) acc[i] = 0.f;
  if (j == 0) {  // self loop
    uint4 a = h4[(size_t)node * 8 + l * 2];
    uint4 b = h4[(size_t)node * 8 + l * 2 + 1];
    add8(acc, a);
    add8(acc + 8, b);
  }
  int e1 = off[node + 1];
  for (int ee = off[node] + j; ee < e1; ee += 16) {
    int s = __builtin_nontemporal_load(&csr[ee]);
    uint4 a = h4[(size_t)s * 8 + l * 2];
    uint4 b = h4[(size_t)s * 8 + l * 2 + 1];
    add8(acc, a);
    add8(acc + 8, b);
  }
  // recursive-halving reduce over the 16 slots; feature count 16 -> 1
#pragma unroll
  for (int i = 0; i < 8; ++i) {
    float tlo = acc[i]     + __shfl_xor(acc[i], 4);
    float thi = acc[i + 8] + __shfl_xor(acc[i + 8], 4);
    acc[i] = (j & 1) ? thi : tlo;
  }
#pragma unroll
  for (int i = 0; i < 4; ++i) {
    float tlo = acc[i]     + __shfl_xor(acc[i], 8);
    float thi = acc[i + 4] + __shfl_xor(acc[i + 4], 8);
    acc[i] = (j & 2) ? thi : tlo;
  }
#pragma unroll
  for (int i = 0; i < 2; ++i) {
    float tlo = acc[i]     + __shfl_xor(acc[i], 16);
    float thi = acc[i + 2] + __shfl_xor(acc[i + 2], 16);
    acc[i] = (j & 4) ? thi : tlo;
  }
  float a0, a1;
  a0 = acc[0] + __shfl_xor(acc[0], 32);
  a1 = acc[1] + __shfl_xor(acc[1], 32);
  float a = (j & 8) ? a1 : a0;
  // this lane now owns feature f = l*16 + j0*8 + j1*4 + j2*2 + j3
  int f = l * 16 + ((j & 1) << 3) + ((j & 2) << 1) + ((j >> 2) & 1) * 2 + ((j >> 3) & 1);
  float di = dinv[node];
  float val;
  if (EPI) {
    val = di * tanhf(fmaf(di, a, bias[f]));
  } else {
    val = di * a;
  }
  // pack feature pairs (f even with f+1, partner lane = lane^32) and store
  float pv = __shfl_xor(val, 32);
  if (!(j & 8)) {  // f even
    unsigned int w = pack_bf16(val, pv);
    int half = l * 8 + ((j & 1) << 2) + (j & 2) + ((j >> 2) & 1);  // f/2
    out[(size_t)node * 32 + half] = w;
  }
}

// ---------- final: mean/logvar GEMMs + reparam ----------
__global__ __launch_bounds__(256) void final_kernel(const unsigned int* __restrict__ aggb,
    const float* __restrict__ Wm, const float* __restrict__ bm,
    const float* __restrict__ Wv, const float* __restrict__ bv,
    const float* __restrict__ noise, float* __restrict__ outZ,
    float* __restrict__ outM, float* __restrict__ outLv, int n) {
  __shared__ float WmS[64 * 32];
  __shared__ float WvS[64 * 32];
  __shared__ float aggS[64 * 68];  // stride 68 breaks bank conflicts
  for (int i = threadIdx.x; i < 64 * 8; i += 256) {
    ((float4*)WmS)[i] = ((const float4*)Wm)[i];
    ((float4*)WvS)[i] = ((const float4*)Wv)[i];
  }
  int row0 = blockIdx.x * 64;
  int nrow = n - row0; if (nrow > 64) nrow = 64;
  for (int i = threadIdx.x; i < 64 * 16; i += 256) {
    int r = i >> 4, g = i & 15;
    uint2 u = make_uint2(0u, 0u);
    if (r < nrow) u = ((const uint2*)aggb)[(size_t)(row0 + r) * 16 + g];
    float* d = &aggS[r * 68 + g * 4];
    d[0] = __uint_as_float(u.x << 16);
    d[1] = __uint_as_float(u.x & 0xFFFF0000u);
    d[2] = __uint_as_float(u.y << 16);
    d[3] = __uint_as_float(u.y & 0xFFFF0000u);
  }
  __syncthreads();
  int c4 = (threadIdx.x & 7) * 4;
  int r2 = (threadIdx.x >> 3) * 2;
  float4 am[2], av[2];
#pragma unroll
  for (int i = 0; i < 2; ++i) {
    am[i] = make_float4(0.f, 0.f, 0.f, 0.f);
    av[i] = make_float4(0.f, 0.f, 0.f, 0.f);
  }
#pragma unroll 4
  for (int kq = 0; kq < 16; ++kq) {
    float4 xa[2], wm[4], wv[4];
#pragma unroll
    for (int i = 0; i < 2; ++i) xa[i] = *(const float4*)&aggS[(r2 + i) * 68 + kq * 4];
#pragma unroll
    for (int q = 0; q < 4; ++q) {
      wm[q] = *(const float4*)&WmS[(kq * 4 + q) * 32 + c4];
      wv[q] = *(const float4*)&WvS[(kq * 4 + q) * 32 + c4];
    }
#pragma unroll
    for (int i = 0; i < 2; ++i) {
      fma4(am[i], xa[i].x, wm[0]); fma4(am[i], xa[i].y, wm[1]);
      fma4(am[i], xa[i].z, wm[2]); fma4(am[i], xa[i].w, wm[3]);
      fma4(av[i], xa[i].x, wv[0]); fma4(av[i], xa[i].y, wv[1]);
      fma4(av[i], xa[i].z, wv[2]); fma4(av[i], xa[i].w, wv[3]);
    }
  }
  float4 bmv = *(const float4*)&bm[c4];
  float4 bvv = *(const float4*)&bv[c4];
#pragma unroll
  for (int i = 0; i < 2; ++i) {
    int row = row0 + r2 + i;
    if (row < n) {
      float4 m = am[i]; m.x += bmv.x; m.y += bmv.y; m.z += bmv.z; m.w += bmv.w;
      float4 v = av[i]; v.x += bvv.x; v.y += bvv.y; v.z += bvv.z; v.w += bvv.w;
      size_t oi = (size_t)row * 8 + (threadIdx.x & 7);
      float4 nz = ((const float4*)noise)[oi];
      float4 z;
      z.x = fmaf(nz.x, expf(0.5f * v.x), m.x);
      z.y = fmaf(nz.y, expf(0.5f * v.y), m.y);
      z.z = fmaf(nz.z, expf(0.5f * v.z), m.z);
      z.w = fmaf(nz.w, expf(0.5f * v.w), m.w);
      ((float4*)outZ)[oi] = z;
      ((float4*)outM)[oi] = m;
      ((float4*)outLv)[oi] = v;
    }
  }
}

// ---------- launch ----------

extern "C" void kernel_launch(void* const* d_in, const int* in_sizes, int n_in,
                              void* d_out, int out_size, void* d_ws, size_t ws_size,
                              hipStream_t stream) {
  const float* x     = (const float*)d_in[0];
  const int*   edge  = (const int*)d_in[1];
  const float* W1    = (const float*)d_in[2];
  const float* b1    = (const float*)d_in[3];
  const float* Wm    = (const float*)d_in[4];
  const float* bm    = (const float*)d_in[5];
  const float* Wv    = (const float*)d_in[6];
  const float* bv    = (const float*)d_in[7];
  const float* noise = (const float*)d_in[8];
  int n = in_sizes[0] / 128;
  int e = in_sizes[1] / 2;
  const int* src = edge;
  const int* dst = edge + e;
  int nc = (n + CMASK) >> CSHIFT;   // 49 coarse buckets of 2048 nodes

  // workspace layout (int units, 16B-aligned segments)
  int* ccnt = (int*)d_ws;                          // NCMAX*16 (1 per 64B line)
  int* ccur = ccnt + NCMAX * 16;                   // NCMAX*16
  int* coff = ccur + NCMAX * 16;                   // NCMAX+1 (+pad)
  int* off  = coff + (NCMAX + 4);                  // n+1 (+pad)
  float* dinv = (float*)(off + ((n + 4) & ~3));    // n
  unsigned int* packed = (unsigned int*)(dinv + ((n + 3) & ~3)); // e
  int* csr  = (int*)(packed + ((e + 3) & ~3));     // e
  unsigned int* h1b = (unsigned int*)(csr + ((e + 3) & ~3)); // n*32 (bf16 h1')
  unsigned int* hb  = h1b + (size_t)n * 32;                  // n*32 (bf16 h')
  unsigned int* aggb = hb + (size_t)n * 32;                  // n*32 (bf16 agg2)

  float* outZ  = (float*)d_out;
  float* outM  = outZ + (size_t)n * 32;
  float* outLv = outM + (size_t)n * 32;

  int ntiles = (e + TILE - 1) / TILE;

  zero_kernel<<<(NCMAX * 16 + 255) / 256, 256, 0, stream>>>(ccnt, NCMAX * 16);
  coarse_hist_kernel<<<256, 256, 0, stream>>>(dst, ccnt, e);
  coarse_scan_kernel<<<1, 64, 0, stream>>>(ccnt, coff, ccur, off, nc, n, e);
  coarse_partition_kernel<<<ntiles, 256, 0, stream>>>(src, dst, ccur, packed, e);
  csr_fine_kernel<<<nc, 512, 0, stream>>>(packed, coff, off, dinv, csr, n);
  gemm1_kernel<<<768, 256, 0, stream>>>(x, W1, dinv, h1b, n);
  agg_kernel<1><<<(n + 3) / 4, 256, 0, stream>>>((const uint4*)h1b, off, csr, dinv, b1, hb, n);
  agg_kernel<0><<<(n + 3) / 4, 256, 0, stream>>>((const uint4*)hb, off, csr, dinv, b1, aggb, n);
  final_kernel<<<(n + 63) / 64, 256, 0, stream>>>(aggb, Wm, bm, Wv, bv, noise, outZ, outM, outLv, n);
}